// Round 16
// baseline (712.590 us; speedup 1.0000x reference)
//
#include <hip/hip_runtime.h>
#include <hip/hip_bf16.h>

#define B_   32
#define T_   128
#define H_   700
#define E_   100
#define G3   2100
#define V_   32000
#define DY_  200
#define DZ_  500
#define KP   704
#define NBLK 88
#define JW   8
#define FSTR 16
#define BT   4096
#define NGRID 288
#define NTILE (32 * 250)

typedef __attribute__((ext_vector_type(8))) short bf16x8;
typedef __attribute__((ext_vector_type(4))) float f32x4;
typedef __attribute__((ext_vector_type(4))) unsigned u32x4;

__device__ __forceinline__ unsigned ld_flag(const unsigned* p) {
    return __hip_atomic_load(p, __ATOMIC_RELAXED, __HIP_MEMORY_SCOPE_AGENT);
}
__device__ __forceinline__ void st_flag(unsigned* p, unsigned v) {
    __hip_atomic_store(p, v, __ATOMIC_RELAXED, __HIP_MEMORY_SCOPE_AGENT);
}
__device__ __forceinline__ void split_bf(float v, short& hi, short& lo) {
    __hip_bfloat16 h = __float2bfloat16(v);
    float r = v - __bfloat162float(h);
    __hip_bfloat16 l = __float2bfloat16(r);
    hi = *reinterpret_cast<short*>(&h);
    lo = *reinterpret_cast<short*>(&l);
}

#define GLDS16(g, l) __builtin_amdgcn_global_load_lds(                            \
        (const __attribute__((address_space(1))) unsigned int*)(g),               \
        (__attribute__((address_space(3))) unsigned int*)(l), 16, 0, 0)

// ---------------- proj_W [700][32000] fp32 -> Wb [32000][704] bf16 ----------------
__global__ __launch_bounds__(256)
void wconv_kernel(const float* __restrict__ W, __hip_bfloat16* __restrict__ Wb) {
    __shared__ float tile[32][33];
    const int n0 = blockIdx.x * 32, k0 = blockIdx.y * 32;
    const int tx = threadIdx.x, ty = threadIdx.y;
    #pragma unroll
    for (int i = 0; i < 4; ++i) {
        int k = k0 + ty + 8 * i;
        float v = (k < H_) ? W[(size_t)k * V_ + n0 + tx] : 0.0f;
        tile[ty + 8 * i][tx] = v;
    }
    __syncthreads();
    #pragma unroll
    for (int i = 0; i < 4; ++i) {
        int nn = ty + 8 * i;
        Wb[(size_t)(n0 + nn) * KP + k0 + tx] = __float2bfloat16(tile[tx][nn]);
    }
}

// ---------------- xpt[c][t*32+b] = (emb-gather @ gru1_k + gb)^T via MFMA hi/lo ----------------
__global__ __launch_bounds__(256)
void xpt_gemm(const int* __restrict__ di, const float* __restrict__ emb,
              const float* __restrict__ gk, const float* __restrict__ gb,
              float* __restrict__ xpt) {
    __shared__ int di_l[64];
    __shared__ unsigned short Bhi[64][136], Blo[64][136];
    const int tid = threadIdx.x;
    const int c0 = blockIdx.x * 64, n0 = blockIdx.y * 64;
    const int wv = tid >> 6, lane = tid & 63, lr = lane & 15, lkg = lane >> 4;

    if (tid < 64) {
        int tb = n0 + tid;
        di_l[tid] = di[(tb & 31) * T_ + (tb >> 5)];
    }
    __syncthreads();
    for (int e = tid; e < 64 * 128; e += 256) {
        int r = e >> 7, k = e & 127;
        float v = (k < E_) ? emb[(size_t)di_l[r] * E_ + k] : 0.0f;
        short hi, lo; split_bf(v, hi, lo);
        Bhi[r][k] = (unsigned short)hi; Blo[r][k] = (unsigned short)lo;
    }
    __syncthreads();

    bf16x8 ahi[4], alo[4];
    const int crow = c0 + wv * 16 + lr;
    #pragma unroll
    for (int kt = 0; kt < 4; ++kt) {
        #pragma unroll
        for (int i = 0; i < 8; ++i) {
            int k = kt * 32 + lkg * 8 + i;
            float v = (k < E_ && crow < G3) ? gk[(size_t)k * G3 + crow] : 0.0f;
            short hi, lo; split_bf(v, hi, lo);
            ahi[kt][i] = hi; alo[kt][i] = lo;
        }
    }
    f32x4 acc[4];
    #pragma unroll
    for (int n = 0; n < 4; ++n) acc[n] = (f32x4){0.f, 0.f, 0.f, 0.f};
    #pragma unroll
    for (int kt = 0; kt < 4; ++kt) {
        #pragma unroll
        for (int n = 0; n < 4; ++n) {
            bf16x8 bh = *(const bf16x8*)&Bhi[n * 16 + lr][kt * 32 + lkg * 8];
            bf16x8 bl = *(const bf16x8*)&Blo[n * 16 + lr][kt * 32 + lkg * 8];
            acc[n] = __builtin_amdgcn_mfma_f32_16x16x32_bf16(ahi[kt], bh, acc[n], 0, 0, 0);
            acc[n] = __builtin_amdgcn_mfma_f32_16x16x32_bf16(ahi[kt], bl, acc[n], 0, 0, 0);
            acc[n] = __builtin_amdgcn_mfma_f32_16x16x32_bf16(alo[kt], bh, acc[n], 0, 0, 0);
        }
    }
    #pragma unroll
    for (int n = 0; n < 4; ++n)
        #pragma unroll
        for (int r = 0; r < 4; ++r) {
            int cr = c0 + wv * 16 + lkg * 4 + r;
            if (cr < G3)
                xpt[(size_t)cr * BT + n0 + n * 16 + lr] = acc[n][r] + gb[cr];
        }
}

// ---------------- mega: 88 GRU blocks + 200 GEMM workers (r14 body, smaller grid) ----------------
// 53.8KB static LDS + launch_bounds(256,2) => capacity 512 >= 288 => all blocks resident.
// 288 blocks on 256 CUs: >=224 CUs single-block => most GRU blocks get an exclusive CU.
__global__ __launch_bounds__(256, 2)
void mega_kernel(const float* __restrict__ labels, const float* __restrict__ zin,
                 const float* __restrict__ W1, const float* __restrict__ b1,
                 const float* __restrict__ xpt, const float* __restrict__ mask,
                 const float* __restrict__ rk, const float* __restrict__ gb,
                 unsigned short* __restrict__ hb, unsigned short* __restrict__ g_out,
                 unsigned* __restrict__ flags, int* __restrict__ wcnt,
                 const __hip_bfloat16* __restrict__ Bw, const float* __restrict__ bias,
                 float* __restrict__ C) {
    __shared__ float part2[4 * 2 * 16 * 33];
    __shared__ float xbuf[24 * 32];
    __shared__ alignas(16) short smhi[32 * 8], smlo[32 * 8], smg[32 * 8];
    __shared__ alignas(16) unsigned short As[128 * 64];
    __shared__ alignas(16) unsigned short Bs[128 * 64];
    __shared__ int s_idx;

    const int tid = threadIdx.x;
    const int blk = blockIdx.x;

    if (blk < NBLK) {
        // ================= GRU role (r14 body, unchanged) ==========
        __builtin_amdgcn_s_setprio(1);
        const int j0 = blk * JW;
        const int wv = tid >> 6, lane = tid & 63, lr = lane & 15, lkg = lane >> 4;
        const int ktb = (wv < 2) ? wv * 6 : 12 + (wv - 2) * 5;
        const int tn  = (wv < 2) ? 6 : 5;

        bf16x8 bhi[2][6], blo[2][6];
        #pragma unroll
        for (int n = 0; n < 2; ++n)
            #pragma unroll
            for (int t = 0; t < 6; ++t) {
                bf16x8 h8, l8;
                int c = n * 16 + lr;
                int gate = c >> 3, jl = c & 7, j = j0 + jl;
                #pragma unroll
                for (int i = 0; i < 8; ++i) {
                    int k = (ktb + t) * 32 + lkg * 8 + i;
                    float v = (t < tn && c < 24 && j < H_ && k < H_)
                                ? rk[(size_t)k * G3 + gate * H_ + j] : 0.0f;
                    short hi, lo; split_bf(v, hi, lo);
                    h8[i] = hi; l8[i] = lo;
                }
                bhi[n][t] = h8; blo[n][t] = l8;
            }

        const int ob = tid & 31, ojl = tid >> 5, oj = j0 + ojl;
        float hold = 0.f, bz = 0.f, brr = 0.f, bh = 0.f;
        if (oj < H_) {
            bz  = gb[G3 + oj];
            brr = gb[G3 + H_ + oj];
            bh  = gb[G3 + 2 * H_ + oj];
            hold = (oj < DY_) ? labels[ob] * W1[oj] + b1[oj] : zin[ob * DZ_ + (oj - DY_)];
        }
        {
            short hi, lo; split_bf(hold, hi, lo);
            smhi[ob * 8 + ojl] = hi; smlo[ob * 8 + ojl] = lo;
        }
        __syncthreads();
        if (tid < 64) {
            int pl = tid >> 5, q = tid & 31;
            u32x4 d = ((const u32x4*)(pl ? smlo : smhi))[q];
            unsigned short* dst = hb + (size_t)blk * 512 + pl * 256 + q * 8;
            asm volatile("global_store_dwordx4 %0, %1, off sc0 sc1" :: "v"(dst), "v"(d) : "memory");
        }
        asm volatile("s_waitcnt vmcnt(0)" ::: "memory");
        __syncthreads();
        if (tid == 0) st_flag(&flags[blk * FSTR], 1u);

        union FragU { u32x4 u; bf16x8 v; };
        struct Chunk { u32x4 a0, l0, a1, l1; };

#define LOADC(T, Cc) do {                                                         \
        const unsigned short* rb = hb + (size_t)cur * 45056                       \
                                     + (size_t)((ktb + (T)) * 4 + lkg) * 512;     \
        asm volatile("global_load_dwordx4 %0, %1, off sc0 sc1"                    \
                     : "=v"((Cc).a0) : "v"(rb + lr * 8) : "memory");              \
        asm volatile("global_load_dwordx4 %0, %1, off sc0 sc1"                    \
                     : "=v"((Cc).l0) : "v"(rb + 256 + lr * 8) : "memory");        \
        asm volatile("global_load_dwordx4 %0, %1, off sc0 sc1"                    \
                     : "=v"((Cc).a1) : "v"(rb + 128 + lr * 8) : "memory");        \
        asm volatile("global_load_dwordx4 %0, %1, off sc0 sc1"                    \
                     : "=v"((Cc).l1) : "v"(rb + 384 + lr * 8) : "memory");        \
    } while (0)
#define PROCC(T, Cc) do {                                                         \
        FragU fa0, fl0, fa1, fl1;                                                 \
        fa0.u = (Cc).a0; fl0.u = (Cc).l0; fa1.u = (Cc).a1; fl1.u = (Cc).l1;       \
        _Pragma("unroll")                                                         \
        for (int n = 0; n < 2; ++n) {                                             \
            acc[0][n] = __builtin_amdgcn_mfma_f32_16x16x32_bf16(fa0.v, bhi[n][T], acc[0][n], 0, 0, 0); \
            acc[0][n] = __builtin_amdgcn_mfma_f32_16x16x32_bf16(fa0.v, blo[n][T], acc[0][n], 0, 0, 0); \
            acc[0][n] = __builtin_amdgcn_mfma_f32_16x16x32_bf16(fl0.v, bhi[n][T], acc[0][n], 0, 0, 0); \
            acc[1][n] = __builtin_amdgcn_mfma_f32_16x16x32_bf16(fa1.v, bhi[n][T], acc[1][n], 0, 0, 0); \
            acc[1][n] = __builtin_amdgcn_mfma_f32_16x16x32_bf16(fa1.v, blo[n][T], acc[1][n], 0, 0, 0); \
            acc[1][n] = __builtin_amdgcn_mfma_f32_16x16x32_bf16(fl1.v, bhi[n][T], acc[1][n], 0, 0, 0); \
        }                                                                         \
    } while (0)
#define VWAIT(N) do { asm volatile("s_waitcnt vmcnt(" #N ")" ::: "memory");       \
                      __builtin_amdgcn_sched_barrier(0); } while (0)

        for (int step = 0; step < T_; ++step) {
            const int cur = step & 1, nxt = cur ^ 1;

            #pragma unroll
            for (int it = 0; it < 3; ++it) {
                int e = tid + it * 256;
                int row = e >> 5, b = e & 31;
                int gate = row >> 3, jl = row & 7, j = j0 + jl;
                xbuf[e] = (j < H_) ? xpt[(size_t)(gate * H_ + j) * BT + step * 32 + b] : 0.f;
            }
            float mvr = (oj < H_) ? mask[(size_t)(ob * T_ + step) * H_ + oj] : 0.f;

            if (tid < NBLK) {
                while (ld_flag(&flags[tid * FSTR]) < (unsigned)(step + 1))
                    __builtin_amdgcn_s_sleep(1);
            }
            __syncthreads();
            VWAIT(0);

            f32x4 acc[2][2];
            #pragma unroll
            for (int m = 0; m < 2; ++m)
                #pragma unroll
                for (int n = 0; n < 2; ++n) acc[m][n] = (f32x4){0.f, 0.f, 0.f, 0.f};
            Chunk c0, c1, c2;
            LOADC(0, c0); LOADC(1, c1); LOADC(2, c2);
            VWAIT(8); PROCC(0, c0); LOADC(3, c0);
            VWAIT(8); PROCC(1, c1); LOADC(4, c1);
            VWAIT(8); PROCC(2, c2); LOADC(5, c2);
            VWAIT(8); PROCC(3, c0);
            VWAIT(4); PROCC(4, c1);
            VWAIT(0); PROCC(5, c2);

            #pragma unroll
            for (int m = 0; m < 2; ++m)
                #pragma unroll
                for (int n = 0; n < 2; ++n)
                    #pragma unroll
                    for (int r = 0; r < 4; ++r)
                        part2[((wv * 2 + m) * 16 + lkg * 4 + r) * 33 + n * 16 + lr] = acc[m][n][r];
            __syncthreads();

            {
                int m = ob >> 4, row = ob & 15;
                float hp0 = bz, hp1 = brr, hp2 = bh;
                #pragma unroll
                for (int w = 0; w < 4; ++w) {
                    int base = ((w * 2 + m) * 16 + row) * 33;
                    hp0 += part2[base + ojl];
                    hp1 += part2[base + 8 + ojl];
                    hp2 += part2[base + 16 + ojl];
                }
                float hn = 0.f, outf = 0.f;
                if (oj < H_) {
                    float xz = xbuf[(0 * 8 + ojl) * 32 + ob];
                    float xr = xbuf[(1 * 8 + ojl) * 32 + ob];
                    float xh = xbuf[(2 * 8 + ojl) * 32 + ob];
                    float zg = 1.0f / (1.0f + expf(-(xz + hp0)));
                    float rg = 1.0f / (1.0f + expf(-(xr + hp1)));
                    float hh = tanhf(xh + rg * hp2);
                    hn = zg * hold + (1.0f - zg) * hh;
                    outf = hn * mvr;
                }
                hold = hn;
                __hip_bfloat16 ov = __float2bfloat16(outf);
                smg[ob * 8 + ojl] = *(short*)&ov;
                short hi, lo; split_bf(hn, hi, lo);
                smhi[ob * 8 + ojl] = hi; smlo[ob * 8 + ojl] = lo;
            }
            __syncthreads();
            if (tid < 64) {
                int pl = tid >> 5, q = tid & 31;
                u32x4 d = ((const u32x4*)(pl ? smlo : smhi))[q];
                unsigned short* dst = hb + (size_t)nxt * 45056 + (size_t)blk * 512 + pl * 256 + q * 8;
                asm volatile("global_store_dwordx4 %0, %1, off sc0 sc1" :: "v"(dst), "v"(d) : "memory");
            } else if (tid < 96) {
                int b = tid - 64;
                u32x4 d = ((const u32x4*)smg)[b];
                unsigned short* gp = g_out + (size_t)(step * 32 + b) * KP + j0;
                asm volatile("global_store_dwordx4 %0, %1, off sc0 sc1" :: "v"(gp), "v"(d) : "memory");
            }
            asm volatile("s_waitcnt vmcnt(0)" ::: "memory");
            __syncthreads();
            if (tid == 0) st_flag(&flags[blk * FSTR], (unsigned)(step + 2));
        }
        __builtin_amdgcn_s_setprio(0);
#undef LOADC
#undef PROCC
#undef VWAIT
    }

    // ================= GEMM worker loop (200 workers + gru blocks joining late) ==========
    {
        const __hip_bfloat16* Ag = (const __hip_bfloat16*)g_out;
        const int lane = tid & 63, w = tid >> 6;
        const int wm = w >> 1, wn = w & 1;
        const int lr = lane & 15, lkg = lane >> 4;
        const int srl = lane >> 3, scol = (lane & 7) * 8;
        unsigned satisfied = 0;
        for (;;) {
            __syncthreads();
            if (tid == 0)
                s_idx = __hip_atomic_fetch_add(wcnt, 1, __ATOMIC_RELAXED, __HIP_MEMORY_SCOPE_AGENT);
            __syncthreads();
            const int idx = s_idx;
            if (idx >= NTILE) break;
            const int m = idx / 250, bn = idx - m * 250;
            const unsigned want = (unsigned)(4 * m + 5);
            if (want > satisfied) {
                if (tid < NBLK) {
                    while (ld_flag(&flags[tid * FSTR]) < want) __builtin_amdgcn_s_sleep(64);
                }
                satisfied = want;
            }
            __syncthreads();
            const int rowbase = m * 128, colbase = bn * 128;

            f32x4 acc[4][4];
            #pragma unroll
            for (int i = 0; i < 4; ++i)
                #pragma unroll
                for (int j = 0; j < 4; ++j) acc[i][j] = (f32x4){0.f, 0.f, 0.f, 0.f};

            for (int kt = 0; kt < 11; ++kt) {
                const int k0 = kt * 64;
                __syncthreads();
                #pragma unroll
                for (int i = 0; i < 4; ++i) {
                    const int r0 = w * 32 + i * 8;
                    GLDS16(&Ag[(size_t)(rowbase + r0 + srl) * KP + k0 + scol], &As[r0 * 64]);
                    GLDS16(&Bw[(size_t)(colbase + r0 + srl) * KP + k0 + scol], &Bs[r0 * 64]);
                }
                __syncthreads();
                #pragma unroll
                for (int ks = 0; ks < 2; ++ks) {
                    bf16x8 af[4], bf[4];
                    #pragma unroll
                    for (int i = 0; i < 4; ++i)
                        af[i] = *(const bf16x8*)&As[(wm * 64 + i * 16 + lr) * 64 + ks * 32 + lkg * 8];
                    #pragma unroll
                    for (int j = 0; j < 4; ++j)
                        bf[j] = *(const bf16x8*)&Bs[(wn * 64 + j * 16 + lr) * 64 + ks * 32 + lkg * 8];
                    #pragma unroll
                    for (int i = 0; i < 4; ++i)
                        #pragma unroll
                        for (int j = 0; j < 4; ++j)
                            acc[i][j] = __builtin_amdgcn_mfma_f32_16x16x32_bf16(af[i], bf[j], acc[i][j], 0, 0, 0);
                }
            }

            float bv[4];
            #pragma unroll
            for (int j = 0; j < 4; ++j) bv[j] = bias[colbase + wn * 64 + j * 16 + lr];
            #pragma unroll
            for (int i = 0; i < 4; ++i) {
                int gr0 = rowbase + wm * 64 + i * 16 + lkg * 4;
                #pragma unroll
                for (int j = 0; j < 4; ++j) {
                    int gcol = colbase + wn * 64 + j * 16 + lr;
                    #pragma unroll
                    for (int r = 0; r < 4; ++r) {
                        int gr = gr0 + r;                       // t-major row = t*32+b
                        int orow = (gr & 31) * T_ + (gr >> 5);  // output row = b*T+t
                        float val = acc[i][j][r] + bv[j];
                        float* cp = &C[(size_t)orow * V_ + gcol];
                        asm volatile("global_store_dword %0, %1, off nt"
                                     :: "v"(cp), "v"(val) : "memory");
                    }
                }
            }
        }
    }
}

extern "C" void kernel_launch(void* const* d_in, const int* in_sizes, int n_in,
                              void* d_out, int out_size, void* d_ws, size_t ws_size,
                              hipStream_t stream) {
    const float* labels = (const float*)d_in[0];
    const float* z      = (const float*)d_in[1];
    const int*   di     = (const int*)d_in[2];
    const float* mask   = (const float*)d_in[3];
    const float* emb    = (const float*)d_in[4];
    const float* W1     = (const float*)d_in[5];
    const float* b1     = (const float*)d_in[6];
    const float* g1k    = (const float*)d_in[7];
    const float* g1rk   = (const float*)d_in[8];
    const float* g1b    = (const float*)d_in[9];
    const float* pW     = (const float*)d_in[10];
    const float* pb     = (const float*)d_in[11];

    // ws layout: 85,415,488 B (proven footprint)
    char* ws = (char*)d_ws;
    unsigned short* g     = (unsigned short*)ws;                    //  5,767,168 (t-major)
    __hip_bfloat16* Wb    = (__hip_bfloat16*)(ws + 5767168);        // 45,056,000
    float*          xpt   = (float*)(ws + 50823168);                // 34,406,400
    unsigned short* hb    = (unsigned short*)(ws + 85229568);       //    180,224
    unsigned*       flags = (unsigned*)(ws + 85409792);             //      5,632
    int*            wcnt  = (int*)(ws + 85415424);                  //         64

    hipMemsetAsync(flags, 0, 5632 + 64, stream);

    xpt_gemm<<<dim3(33, 64), 256, 0, stream>>>(di, emb, g1k, g1b, xpt);
    wconv_kernel<<<dim3(1000, 22), dim3(32, 8), 0, stream>>>(pW, Wb);

    mega_kernel<<<dim3(NGRID), 256, 0, stream>>>(labels, z, W1, b1, xpt, mask,
                                                 g1rk, g1b, hb, g, flags, wcnt,
                                                 Wb, pb, (float*)d_out);
}

// Round 17
// 664.342 us; speedup vs baseline: 1.0726x; 1.0726x over previous
//
#include <hip/hip_runtime.h>
#include <hip/hip_bf16.h>

#define B_   32
#define T_   128
#define H_   700
#define E_   100
#define G3   2100
#define V_   32000
#define DY_  200
#define DZ_  500
#define KP   704
#define NBLK 88
#define JW   8
#define FSTR 16
#define BT   4096
#define NTILE (32 * 250)

typedef __attribute__((ext_vector_type(8))) short bf16x8;
typedef __attribute__((ext_vector_type(4))) float f32x4;
typedef __attribute__((ext_vector_type(4))) unsigned u32x4;

__device__ __forceinline__ unsigned ld_flag(const unsigned* p) {
    return __hip_atomic_load(p, __ATOMIC_RELAXED, __HIP_MEMORY_SCOPE_AGENT);
}
__device__ __forceinline__ void st_flag(unsigned* p, unsigned v) {
    __hip_atomic_store(p, v, __ATOMIC_RELAXED, __HIP_MEMORY_SCOPE_AGENT);
}
__device__ __forceinline__ void split_bf(float v, short& hi, short& lo) {
    __hip_bfloat16 h = __float2bfloat16(v);
    float r = v - __bfloat162float(h);
    __hip_bfloat16 l = __float2bfloat16(r);
    hi = *reinterpret_cast<short*>(&h);
    lo = *reinterpret_cast<short*>(&l);
}

#define GLDS16(g, l) __builtin_amdgcn_global_load_lds(                            \
        (const __attribute__((address_space(1))) unsigned int*)(g),               \
        (__attribute__((address_space(3))) unsigned int*)(l), 16, 0, 0)

// ---------------- proj_W [700][32000] fp32 -> Wb [32000][704] bf16 ----------------
__global__ __launch_bounds__(256)
void wconv_kernel(const float* __restrict__ W, __hip_bfloat16* __restrict__ Wb) {
    __shared__ float tile[32][33];
    const int n0 = blockIdx.x * 32, k0 = blockIdx.y * 32;
    const int tx = threadIdx.x, ty = threadIdx.y;
    #pragma unroll
    for (int i = 0; i < 4; ++i) {
        int k = k0 + ty + 8 * i;
        float v = (k < H_) ? W[(size_t)k * V_ + n0 + tx] : 0.0f;
        tile[ty + 8 * i][tx] = v;
    }
    __syncthreads();
    #pragma unroll
    for (int i = 0; i < 4; ++i) {
        int nn = ty + 8 * i;
        Wb[(size_t)(n0 + nn) * KP + k0 + tx] = __float2bfloat16(tile[tx][nn]);
    }
}

// ---------------- xpt[c][t*32+b] = (emb-gather @ gru1_k + gb)^T via MFMA hi/lo ----------------
__global__ __launch_bounds__(256)
void xpt_gemm(const int* __restrict__ di, const float* __restrict__ emb,
              const float* __restrict__ gk, const float* __restrict__ gb,
              float* __restrict__ xpt) {
    __shared__ int di_l[64];
    __shared__ unsigned short Bhi[64][136], Blo[64][136];
    const int tid = threadIdx.x;
    const int c0 = blockIdx.x * 64, n0 = blockIdx.y * 64;
    const int wv = tid >> 6, lane = tid & 63, lr = lane & 15, lkg = lane >> 4;

    if (tid < 64) {
        int tb = n0 + tid;
        di_l[tid] = di[(tb & 31) * T_ + (tb >> 5)];
    }
    __syncthreads();
    for (int e = tid; e < 64 * 128; e += 256) {
        int r = e >> 7, k = e & 127;
        float v = (k < E_) ? emb[(size_t)di_l[r] * E_ + k] : 0.0f;
        short hi, lo; split_bf(v, hi, lo);
        Bhi[r][k] = (unsigned short)hi; Blo[r][k] = (unsigned short)lo;
    }
    __syncthreads();

    bf16x8 ahi[4], alo[4];
    const int crow = c0 + wv * 16 + lr;
    #pragma unroll
    for (int kt = 0; kt < 4; ++kt) {
        #pragma unroll
        for (int i = 0; i < 8; ++i) {
            int k = kt * 32 + lkg * 8 + i;
            float v = (k < E_ && crow < G3) ? gk[(size_t)k * G3 + crow] : 0.0f;
            short hi, lo; split_bf(v, hi, lo);
            ahi[kt][i] = hi; alo[kt][i] = lo;
        }
    }
    f32x4 acc[4];
    #pragma unroll
    for (int n = 0; n < 4; ++n) acc[n] = (f32x4){0.f, 0.f, 0.f, 0.f};
    #pragma unroll
    for (int kt = 0; kt < 4; ++kt) {
        #pragma unroll
        for (int n = 0; n < 4; ++n) {
            bf16x8 bh = *(const bf16x8*)&Bhi[n * 16 + lr][kt * 32 + lkg * 8];
            bf16x8 bl = *(const bf16x8*)&Blo[n * 16 + lr][kt * 32 + lkg * 8];
            acc[n] = __builtin_amdgcn_mfma_f32_16x16x32_bf16(ahi[kt], bh, acc[n], 0, 0, 0);
            acc[n] = __builtin_amdgcn_mfma_f32_16x16x32_bf16(ahi[kt], bl, acc[n], 0, 0, 0);
            acc[n] = __builtin_amdgcn_mfma_f32_16x16x32_bf16(alo[kt], bh, acc[n], 0, 0, 0);
        }
    }
    #pragma unroll
    for (int n = 0; n < 4; ++n)
        #pragma unroll
        for (int r = 0; r < 4; ++r) {
            int cr = c0 + wv * 16 + lkg * 4 + r;
            if (cr < G3)
                xpt[(size_t)cr * BT + n0 + n * 16 + lr] = acc[n][r] + gb[cr];
        }
}

// ---------------- mega: 88 GRU blocks + 424 persistent GEMM workers (r14 best config) ----------------
// 53.8KB static LDS + launch_bounds(256,2) => exactly 2 blocks/CU => all 512 resident.
// GRU waves at setprio(1); workers cache satisfied-flag level (poll only on m-group advance);
// C stored nt (no L3 eviction of Wb); g published as packed 16B stores.
__global__ __launch_bounds__(256, 2)
void mega_kernel(const float* __restrict__ labels, const float* __restrict__ zin,
                 const float* __restrict__ W1, const float* __restrict__ b1,
                 const float* __restrict__ xpt, const float* __restrict__ mask,
                 const float* __restrict__ rk, const float* __restrict__ gb,
                 unsigned short* __restrict__ hb, unsigned short* __restrict__ g_out,
                 unsigned* __restrict__ flags, int* __restrict__ wcnt,
                 const __hip_bfloat16* __restrict__ Bw, const float* __restrict__ bias,
                 float* __restrict__ C) {
    __shared__ float part2[4 * 2 * 16 * 33];
    __shared__ float xbuf[24 * 32];
    __shared__ alignas(16) short smhi[32 * 8], smlo[32 * 8], smg[32 * 8];
    __shared__ alignas(16) unsigned short As[128 * 64];
    __shared__ alignas(16) unsigned short Bs[128 * 64];
    __shared__ int s_idx;

    const int tid = threadIdx.x;
    const int blk = blockIdx.x;

    if (blk < NBLK) {
        // ================= GRU role ==========
        __builtin_amdgcn_s_setprio(1);
        const int j0 = blk * JW;
        const int wv = tid >> 6, lane = tid & 63, lr = lane & 15, lkg = lane >> 4;
        const int ktb = (wv < 2) ? wv * 6 : 12 + (wv - 2) * 5;
        const int tn  = (wv < 2) ? 6 : 5;

        bf16x8 bhi[2][6], blo[2][6];
        #pragma unroll
        for (int n = 0; n < 2; ++n)
            #pragma unroll
            for (int t = 0; t < 6; ++t) {
                bf16x8 h8, l8;
                int c = n * 16 + lr;
                int gate = c >> 3, jl = c & 7, j = j0 + jl;
                #pragma unroll
                for (int i = 0; i < 8; ++i) {
                    int k = (ktb + t) * 32 + lkg * 8 + i;
                    float v = (t < tn && c < 24 && j < H_ && k < H_)
                                ? rk[(size_t)k * G3 + gate * H_ + j] : 0.0f;
                    short hi, lo; split_bf(v, hi, lo);
                    h8[i] = hi; l8[i] = lo;
                }
                bhi[n][t] = h8; blo[n][t] = l8;
            }

        const int ob = tid & 31, ojl = tid >> 5, oj = j0 + ojl;
        float hold = 0.f, bz = 0.f, brr = 0.f, bh = 0.f;
        if (oj < H_) {
            bz  = gb[G3 + oj];
            brr = gb[G3 + H_ + oj];
            bh  = gb[G3 + 2 * H_ + oj];
            hold = (oj < DY_) ? labels[ob] * W1[oj] + b1[oj] : zin[ob * DZ_ + (oj - DY_)];
        }
        {
            short hi, lo; split_bf(hold, hi, lo);
            smhi[ob * 8 + ojl] = hi; smlo[ob * 8 + ojl] = lo;
        }
        __syncthreads();
        if (tid < 64) {
            int pl = tid >> 5, q = tid & 31;
            u32x4 d = ((const u32x4*)(pl ? smlo : smhi))[q];
            unsigned short* dst = hb + (size_t)blk * 512 + pl * 256 + q * 8;
            asm volatile("global_store_dwordx4 %0, %1, off sc0 sc1" :: "v"(dst), "v"(d) : "memory");
        }
        asm volatile("s_waitcnt vmcnt(0)" ::: "memory");
        __syncthreads();
        if (tid == 0) st_flag(&flags[blk * FSTR], 1u);

        union FragU { u32x4 u; bf16x8 v; };
        struct Chunk { u32x4 a0, l0, a1, l1; };

#define LOADC(T, Cc) do {                                                         \
        const unsigned short* rb = hb + (size_t)cur * 45056                       \
                                     + (size_t)((ktb + (T)) * 4 + lkg) * 512;     \
        asm volatile("global_load_dwordx4 %0, %1, off sc0 sc1"                    \
                     : "=v"((Cc).a0) : "v"(rb + lr * 8) : "memory");              \
        asm volatile("global_load_dwordx4 %0, %1, off sc0 sc1"                    \
                     : "=v"((Cc).l0) : "v"(rb + 256 + lr * 8) : "memory");        \
        asm volatile("global_load_dwordx4 %0, %1, off sc0 sc1"                    \
                     : "=v"((Cc).a1) : "v"(rb + 128 + lr * 8) : "memory");        \
        asm volatile("global_load_dwordx4 %0, %1, off sc0 sc1"                    \
                     : "=v"((Cc).l1) : "v"(rb + 384 + lr * 8) : "memory");        \
    } while (0)
#define PROCC(T, Cc) do {                                                         \
        FragU fa0, fl0, fa1, fl1;                                                 \
        fa0.u = (Cc).a0; fl0.u = (Cc).l0; fa1.u = (Cc).a1; fl1.u = (Cc).l1;       \
        _Pragma("unroll")                                                         \
        for (int n = 0; n < 2; ++n) {                                             \
            acc[0][n] = __builtin_amdgcn_mfma_f32_16x16x32_bf16(fa0.v, bhi[n][T], acc[0][n], 0, 0, 0); \
            acc[0][n] = __builtin_amdgcn_mfma_f32_16x16x32_bf16(fa0.v, blo[n][T], acc[0][n], 0, 0, 0); \
            acc[0][n] = __builtin_amdgcn_mfma_f32_16x16x32_bf16(fl0.v, bhi[n][T], acc[0][n], 0, 0, 0); \
            acc[1][n] = __builtin_amdgcn_mfma_f32_16x16x32_bf16(fa1.v, bhi[n][T], acc[1][n], 0, 0, 0); \
            acc[1][n] = __builtin_amdgcn_mfma_f32_16x16x32_bf16(fa1.v, blo[n][T], acc[1][n], 0, 0, 0); \
            acc[1][n] = __builtin_amdgcn_mfma_f32_16x16x32_bf16(fl1.v, bhi[n][T], acc[1][n], 0, 0, 0); \
        }                                                                         \
    } while (0)
#define VWAIT(N) do { asm volatile("s_waitcnt vmcnt(" #N ")" ::: "memory");       \
                      __builtin_amdgcn_sched_barrier(0); } while (0)

        for (int step = 0; step < T_; ++step) {
            const int cur = step & 1, nxt = cur ^ 1;

            #pragma unroll
            for (int it = 0; it < 3; ++it) {
                int e = tid + it * 256;
                int row = e >> 5, b = e & 31;
                int gate = row >> 3, jl = row & 7, j = j0 + jl;
                xbuf[e] = (j < H_) ? xpt[(size_t)(gate * H_ + j) * BT + step * 32 + b] : 0.f;
            }
            float mvr = (oj < H_) ? mask[(size_t)(ob * T_ + step) * H_ + oj] : 0.f;

            if (tid < NBLK) {
                while (ld_flag(&flags[tid * FSTR]) < (unsigned)(step + 1))
                    __builtin_amdgcn_s_sleep(1);
            }
            __syncthreads();
            VWAIT(0);

            f32x4 acc[2][2];
            #pragma unroll
            for (int m = 0; m < 2; ++m)
                #pragma unroll
                for (int n = 0; n < 2; ++n) acc[m][n] = (f32x4){0.f, 0.f, 0.f, 0.f};
            Chunk c0, c1, c2;
            LOADC(0, c0); LOADC(1, c1); LOADC(2, c2);
            VWAIT(8); PROCC(0, c0); LOADC(3, c0);
            VWAIT(8); PROCC(1, c1); LOADC(4, c1);
            VWAIT(8); PROCC(2, c2); LOADC(5, c2);
            VWAIT(8); PROCC(3, c0);
            VWAIT(4); PROCC(4, c1);
            VWAIT(0); PROCC(5, c2);

            #pragma unroll
            for (int m = 0; m < 2; ++m)
                #pragma unroll
                for (int n = 0; n < 2; ++n)
                    #pragma unroll
                    for (int r = 0; r < 4; ++r)
                        part2[((wv * 2 + m) * 16 + lkg * 4 + r) * 33 + n * 16 + lr] = acc[m][n][r];
            __syncthreads();

            {
                int m = ob >> 4, row = ob & 15;
                float hp0 = bz, hp1 = brr, hp2 = bh;
                #pragma unroll
                for (int w = 0; w < 4; ++w) {
                    int base = ((w * 2 + m) * 16 + row) * 33;
                    hp0 += part2[base + ojl];
                    hp1 += part2[base + 8 + ojl];
                    hp2 += part2[base + 16 + ojl];
                }
                float hn = 0.f, outf = 0.f;
                if (oj < H_) {
                    float xz = xbuf[(0 * 8 + ojl) * 32 + ob];
                    float xr = xbuf[(1 * 8 + ojl) * 32 + ob];
                    float xh = xbuf[(2 * 8 + ojl) * 32 + ob];
                    float zg = 1.0f / (1.0f + expf(-(xz + hp0)));
                    float rg = 1.0f / (1.0f + expf(-(xr + hp1)));
                    float hh = tanhf(xh + rg * hp2);
                    hn = zg * hold + (1.0f - zg) * hh;
                    outf = hn * mvr;
                }
                hold = hn;
                __hip_bfloat16 ov = __float2bfloat16(outf);
                smg[ob * 8 + ojl] = *(short*)&ov;
                short hi, lo; split_bf(hn, hi, lo);
                smhi[ob * 8 + ojl] = hi; smlo[ob * 8 + ojl] = lo;
            }
            __syncthreads();
            if (tid < 64) {
                int pl = tid >> 5, q = tid & 31;
                u32x4 d = ((const u32x4*)(pl ? smlo : smhi))[q];
                unsigned short* dst = hb + (size_t)nxt * 45056 + (size_t)blk * 512 + pl * 256 + q * 8;
                asm volatile("global_store_dwordx4 %0, %1, off sc0 sc1" :: "v"(dst), "v"(d) : "memory");
            } else if (tid < 96) {
                int b = tid - 64;                       // g row (step*32+b), 16B at col j0
                u32x4 d = ((const u32x4*)smg)[b];
                unsigned short* gp = g_out + (size_t)(step * 32 + b) * KP + j0;
                asm volatile("global_store_dwordx4 %0, %1, off sc0 sc1" :: "v"(gp), "v"(d) : "memory");
            }
            asm volatile("s_waitcnt vmcnt(0)" ::: "memory");
            __syncthreads();
            if (tid == 0) st_flag(&flags[blk * FSTR], (unsigned)(step + 2));
        }
        __builtin_amdgcn_s_setprio(0);
#undef LOADC
#undef PROCC
#undef VWAIT
    }

    // ================= GEMM worker loop (all blocks; gru blocks join late) ==========
    {
        const __hip_bfloat16* Ag = (const __hip_bfloat16*)g_out;
        const int lane = tid & 63, w = tid >> 6;
        const int wm = w >> 1, wn = w & 1;
        const int lr = lane & 15, lkg = lane >> 4;
        const int srl = lane >> 3, scol = (lane & 7) * 8;
        unsigned satisfied = 0;                      // cached min flag level (uniform)
        for (;;) {
            __syncthreads();
            if (tid == 0)
                s_idx = __hip_atomic_fetch_add(wcnt, 1, __ATOMIC_RELAXED, __HIP_MEMORY_SCOPE_AGENT);
            __syncthreads();
            const int idx = s_idx;
            if (idx >= NTILE) break;
            const int m = idx / 250, bn = idx - m * 250;
            const unsigned want = (unsigned)(4 * m + 5);
            if (want > satisfied) {                  // poll only on m-group advance
                if (tid < NBLK) {
                    while (ld_flag(&flags[tid * FSTR]) < want) __builtin_amdgcn_s_sleep(64);
                }
                satisfied = want;
            }
            __syncthreads();
            const int rowbase = m * 128, colbase = bn * 128;

            f32x4 acc[4][4];
            #pragma unroll
            for (int i = 0; i < 4; ++i)
                #pragma unroll
                for (int j = 0; j < 4; ++j) acc[i][j] = (f32x4){0.f, 0.f, 0.f, 0.f};

            for (int kt = 0; kt < 11; ++kt) {
                const int k0 = kt * 64;
                __syncthreads();
                #pragma unroll
                for (int i = 0; i < 4; ++i) {
                    const int r0 = w * 32 + i * 8;
                    GLDS16(&Ag[(size_t)(rowbase + r0 + srl) * KP + k0 + scol], &As[r0 * 64]);
                    GLDS16(&Bw[(size_t)(colbase + r0 + srl) * KP + k0 + scol], &Bs[r0 * 64]);
                }
                __syncthreads();
                #pragma unroll
                for (int ks = 0; ks < 2; ++ks) {
                    bf16x8 af[4], bf[4];
                    #pragma unroll
                    for (int i = 0; i < 4; ++i)
                        af[i] = *(const bf16x8*)&As[(wm * 64 + i * 16 + lr) * 64 + ks * 32 + lkg * 8];
                    #pragma unroll
                    for (int j = 0; j < 4; ++j)
                        bf[j] = *(const bf16x8*)&Bs[(wn * 64 + j * 16 + lr) * 64 + ks * 32 + lkg * 8];
                    #pragma unroll
                    for (int i = 0; i < 4; ++i)
                        #pragma unroll
                        for (int j = 0; j < 4; ++j)
                            acc[i][j] = __builtin_amdgcn_mfma_f32_16x16x32_bf16(af[i], bf[j], acc[i][j], 0, 0, 0);
                }
            }

            float bv[4];
            #pragma unroll
            for (int j = 0; j < 4; ++j) bv[j] = bias[colbase + wn * 64 + j * 16 + lr];
            #pragma unroll
            for (int i = 0; i < 4; ++i) {
                int gr0 = rowbase + wm * 64 + i * 16 + lkg * 4;
                #pragma unroll
                for (int j = 0; j < 4; ++j) {
                    int gcol = colbase + wn * 64 + j * 16 + lr;
                    #pragma unroll
                    for (int r = 0; r < 4; ++r) {
                        int gr = gr0 + r;                       // t-major row = t*32+b
                        int orow = (gr & 31) * T_ + (gr >> 5);  // output row = b*T+t
                        float val = acc[i][j][r] + bv[j];
                        float* cp = &C[(size_t)orow * V_ + gcol];
                        asm volatile("global_store_dword %0, %1, off nt"
                                     :: "v"(cp), "v"(val) : "memory");
                    }
                }
            }
        }
    }
}

extern "C" void kernel_launch(void* const* d_in, const int* in_sizes, int n_in,
                              void* d_out, int out_size, void* d_ws, size_t ws_size,
                              hipStream_t stream) {
    const float* labels = (const float*)d_in[0];
    const float* z      = (const float*)d_in[1];
    const int*   di     = (const int*)d_in[2];
    const float* mask   = (const float*)d_in[3];
    const float* emb    = (const float*)d_in[4];
    const float* W1     = (const float*)d_in[5];
    const float* b1     = (const float*)d_in[6];
    const float* g1k    = (const float*)d_in[7];
    const float* g1rk   = (const float*)d_in[8];
    const float* g1b    = (const float*)d_in[9];
    const float* pW     = (const float*)d_in[10];
    const float* pb     = (const float*)d_in[11];

    // ws layout: 85,415,488 B (proven footprint)
    char* ws = (char*)d_ws;
    unsigned short* g     = (unsigned short*)ws;                    //  5,767,168 (t-major)
    __hip_bfloat16* Wb    = (__hip_bfloat16*)(ws + 5767168);        // 45,056,000
    float*          xpt   = (float*)(ws + 50823168);                // 34,406,400
    unsigned short* hb    = (unsigned short*)(ws + 85229568);       //    180,224
    unsigned*       flags = (unsigned*)(ws + 85409792);             //      5,632
    int*            wcnt  = (int*)(ws + 85415424);                  //         64

    hipMemsetAsync(flags, 0, 5632 + 64, stream);

    xpt_gemm<<<dim3(33, 64), 256, 0, stream>>>(di, emb, g1k, g1b, xpt);
    wconv_kernel<<<dim3(1000, 22), dim3(32, 8), 0, stream>>>(pW, Wb);

    mega_kernel<<<dim3(512), 256, 0, stream>>>(labels, z, W1, b1, xpt, mask,
                                               g1rk, g1b, hb, g, flags, wcnt,
                                               Wb, pb, (float*)d_out);
}